// Round 5
// baseline (1870.337 us; speedup 1.0000x reference)
//
#include <hip/hip_runtime.h>
#include <cstdio>

#define DIN   1024
#define DHID  4096
#define DOUT  1024
#define NEXP  16
#define NTOK  8192
#define NPAIR (NTOK * 2)
#define PADMAX 20480          // 16384 + 16*255 rounded up to 256
#define MAXTILES 80           // max sum of per-expert ceil(cnt/256)

typedef _Float16 h8 __attribute__((ext_vector_type(8)));
typedef _Float16 h4 __attribute__((ext_vector_type(4)));
typedef float    f4 __attribute__((ext_vector_type(4)));

// ctrl[] int indices
#define C_CNT  0    // [16] per-expert pair counts
#define C_POFF 16   // [16] padded segment offsets
#define C_CUR  32   // [16] assignment cursors
#define C_NT   48   // total tiles
#define C_TE   64   // [80] tile -> expert
#define C_TP   256  // [80] tile -> p0 (padded row start)

__device__ __forceinline__ void async16(const void* g, void* l) {
  __builtin_amdgcn_global_load_lds((const __attribute__((address_space(1))) void*)g,
                                   (__attribute__((address_space(3))) void*)l, 16, 0, 0);
}

// ---- init: zero out, convert x->fp16, default perm, zero ctrl ----
__global__ void k_init(float* __restrict__ out, const float* __restrict__ x,
                       _Float16* __restrict__ x16, int* __restrict__ ptok,
                       float* __restrict__ pw, int* __restrict__ ctrl) {
  int i = blockIdx.x * 256 + threadIdx.x;           // 2,097,152 threads
  ((f4*)out)[i] = (f4){0.f, 0.f, 0.f, 0.f};
  float4 v = ((const float4*)x)[i];
  h4 hv = {(_Float16)v.x, (_Float16)v.y, (_Float16)v.z, (_Float16)v.w};
  ((h4*)x16)[i] = hv;
  if (i < PADMAX) { ptok[i] = 0; pw[i] = 0.f; }
  if (i < 1024) ctrl[i] = 0;
}

// ---- gating: logits, top-2, softmax weights, counts. 1 wave/token ----
__global__ void k_gate(const float* __restrict__ x, const float* __restrict__ wg,
                       int* __restrict__ te, float* __restrict__ tw,
                       int* __restrict__ ctrl) {
  int t = blockIdx.x * 4 + (threadIdx.x >> 6);
  int l = threadIdx.x & 63;
  const float* xr = x + (long)t * DIN;
  float acc[NEXP];
#pragma unroll
  for (int e = 0; e < NEXP; ++e) acc[e] = 0.f;
  for (int k = l; k < DIN; k += 64) {
    float xv = xr[k];
    const float4* wr = (const float4*)(wg + (long)k * NEXP);
    float4 a = wr[0], b = wr[1], c = wr[2], d = wr[3];
    acc[0]  += xv * a.x; acc[1]  += xv * a.y; acc[2]  += xv * a.z; acc[3]  += xv * a.w;
    acc[4]  += xv * b.x; acc[5]  += xv * b.y; acc[6]  += xv * b.z; acc[7]  += xv * b.w;
    acc[8]  += xv * c.x; acc[9]  += xv * c.y; acc[10] += xv * c.z; acc[11] += xv * c.w;
    acc[12] += xv * d.x; acc[13] += xv * d.y; acc[14] += xv * d.z; acc[15] += xv * d.w;
  }
#pragma unroll
  for (int off = 32; off > 0; off >>= 1) {
#pragma unroll
    for (int e = 0; e < NEXP; ++e) acc[e] += __shfl_xor(acc[e], off, 64);
  }
  if (l == 0) {
    float v0 = -1e30f; int e0 = 0;
#pragma unroll
    for (int e = 0; e < NEXP; ++e) if (acc[e] > v0) { v0 = acc[e]; e0 = e; }
    float v1 = -1e30f; int e1 = 0;
#pragma unroll
    for (int e = 0; e < NEXP; ++e) if (e != e0 && acc[e] > v1) { v1 = acc[e]; e1 = e; }
    float d = expf(v1 - v0);
    float den = 1.f / (1.f + d);
    te[2 * t] = e0;     tw[2 * t] = den;       // w0 (top-1)
    te[2 * t + 1] = e1; tw[2 * t + 1] = d * den;
    atomicAdd(&ctrl[C_CNT + e0], 1);
    atomicAdd(&ctrl[C_CNT + e1], 1);
  }
}

// ---- scan: padded offsets (256-granular), cursors, tile table ----
__global__ void k_scan(int* __restrict__ ctrl) {
  __shared__ int sOff[NEXP], sT0[NEXP], sTiles[NEXP];
  int tid = threadIdx.x;
  if (tid == 0) {
    int off = 0, nt = 0;
    for (int e = 0; e < NEXP; ++e) {
      int c = ctrl[C_CNT + e];
      int tiles = (c + 255) >> 8;
      ctrl[C_POFF + e] = off;
      ctrl[C_CUR + e] = off;
      sOff[e] = off; sT0[e] = nt; sTiles[e] = tiles;
      nt += tiles;
      off += tiles * 256;
    }
    ctrl[C_NT] = nt;
  }
  __syncthreads();
  int nt = sT0[NEXP - 1] + sTiles[NEXP - 1];
  for (int j = tid; j < nt; j += blockDim.x) {
    int e = 0;
#pragma unroll
    for (int k = 1; k < NEXP; ++k) if (j >= sT0[k]) e = k;
    ctrl[C_TE + j] = e;
    ctrl[C_TP + j] = sOff[e] + (j - sT0[e]) * 256;
  }
}

// ---- assign: fill permuted pair arrays ----
__global__ void k_assign(const int* __restrict__ te, const float* __restrict__ tw,
                         int* __restrict__ ctrl, int* __restrict__ ptok,
                         float* __restrict__ pw) {
  int t = blockIdx.x * 256 + threadIdx.x;
#pragma unroll
  for (int s = 0; s < 2; ++s) {
    int e = te[2 * t + s];
    int pos = atomicAdd(&ctrl[C_CUR + e], 1);
    ptok[pos] = t;
    pw[pos] = tw[2 * t + s];
  }
}

// ---- grouped GEMM: 256x256 tile, BK=64, 8 waves (2Mx4N), 8-phase schedule ----
// NO pre-transpose: B staged directly from native W[e][k][n] fp32.
//   A: global_load_lds fp16 (x16 / H), 2 tiles ahead, in-place dbuf juggling.
//   B: reg-staged: 8x float4 (two 4kx4n micro-tiles) -> in-register transpose ->
//      8x ds_write_b64 into the SAME XOR-swizzled [n][k] fp16 layout readB uses
//      (elem k of row r in chunk (k>>3)^(r&7); write chunk (kb>>1)^(r&7), sub (kb&1)*4).
//   Pipeline: loadB(t+2) issued at P4(t) after writeB(t+1) (4-phase cover).
//   Counted waits (all VMEM issues fenced by "memory" asm, counts exact):
//     P4 steady: vmcnt(4) = A(t+2) newer than {B(t+1), A(t+1)} being waited.
// 1D grid, bijective XCD chunk swizzle, mt-fastest (L2 B-slice sharing).
template<int KD, int ND, int G1>
__global__ __launch_bounds__(512, 2)
void k_gemm(const _Float16* __restrict__ A, const float* __restrict__ W,
            const float* __restrict__ bias, const int* __restrict__ ctrl,
            const int* __restrict__ ptok, const float* __restrict__ pw,
            _Float16* __restrict__ Hout, float* __restrict__ out) {
  __shared__ __align__(16) _Float16 sm[65536];   // 128 KB

  constexpr int NWK = (ND / 256) * MAXTILES;
  constexpr int QX = NWK / 8;                    // chunk per XCD
  int bid = blockIdx.x;
  int wid = (bid & 7) * QX + (bid >> 3);         // bijective XCD chunk swizzle
  int mt = wid % MAXTILES;
  int nb = wid / MAXTILES;

  if (mt >= ctrl[C_NT]) return;
  int e  = ctrl[C_TE + mt];
  int p0 = ctrl[C_TP + mt];
  int n0 = nb * 256;
  int tid = threadIdx.x;
  int w = tid >> 6, l = tid & 63;
  int wm = w & 1, wn = w >> 1;           // 2 M-warps x 4 N-warps
  int ln15 = l & 15, lq = l >> 4;

  // ---- A staging pointers (async16): halves h=0,1, slots j=0,1 ----
  const _Float16* agp[4];
#pragma unroll
  for (int h = 0; h < 2; ++h)
#pragma unroll
    for (int j = 0; j < 2; ++j) {
      int r = (w * 2 + j) * 8 + (l >> 3);          // row in half, 0..127
      int c = (l & 7) ^ (r & 7);                   // swizzle-on-source
      long arow = G1 ? (long)ptok[p0 + h * 128 + r] : (long)(p0 + h * 128 + r);
      agp[h * 2 + j] = A + arow * KD + c * 8;
    }
  auto stageA = [&](int t, int h) {
    _Float16* dst = sm + (t & 1) * 32768 + h * 8192 + w * 1024;
    long koff = (long)t * 64;
    async16(agp[h * 2 + 0] + koff, dst);
    async16(agp[h * 2 + 1] + koff, dst + 512);
  };

  // ---- B reg-staging: thread covers k-quad kb (0..15), n-quads nq4, nq4+32 ----
  int kb  = (w & 3) * 4 + lq;            // 0..15 -> k rows kb*4..kb*4+3
  int nq4 = (l & 15) + (w >> 2) * 16;    // 0..31 -> n cols nq4*4..+3 (and +128)
  const float* gB0 = W + ((long)e * KD + kb * 4) * ND + n0 + nq4 * 4;
  const float* gB1 = gB0 + 128;
  int bwo[2][4];                         // LDS elem offsets (sans dbuf select)
#pragma unroll
  for (int it = 0; it < 2; ++it)
#pragma unroll
    for (int j = 0; j < 4; ++j) {
      int r = (nq4 + it * 32) * 4 + j;   // 0..255
      bwo[it][j] = 16384 + (r >> 7) * 8192 + (r & 127) * 64
                 + (((kb >> 1) ^ (r & 7)) << 3) + (kb & 1) * 4;
    }
  f4 breg[8];
  auto loadB = [&](int t) {
    const float* pa = gB0 + (long)t * 64 * ND;
    const float* pb = gB1 + (long)t * 64 * ND;
#pragma unroll
    for (int i = 0; i < 4; ++i) {
      breg[i]     = *(const f4*)(pa + (long)i * ND);
      breg[4 + i] = *(const f4*)(pb + (long)i * ND);
    }
  };
  auto writeB = [&](int t) {             // in-register 4x4 transpose -> b64 writes
    _Float16* dstb = sm + (t & 1) * 32768;
#pragma unroll
    for (int it = 0; it < 2; ++it)
#pragma unroll
      for (int j = 0; j < 4; ++j) {
        h4 hv = {(_Float16)breg[it * 4 + 0][j], (_Float16)breg[it * 4 + 1][j],
                 (_Float16)breg[it * 4 + 2][j], (_Float16)breg[it * 4 + 3][j]};
        *(h4*)&dstb[bwo[it][j]] = hv;
      }
  };

  f4 acc[2][4][2][2];
#pragma unroll
  for (int mq = 0; mq < 2; ++mq)
#pragma unroll
    for (int i = 0; i < 4; ++i)
#pragma unroll
      for (int nq = 0; nq < 2; ++nq)
#pragma unroll
        for (int j = 0; j < 2; ++j) acc[mq][i][nq][j] = (f4){0.f, 0.f, 0.f, 0.f};

  h8 af[8], bf0[4], bf1[4];

  auto readA = [&](int d, int mq) {     // 8 x ds_read_b128
    const _Float16* Ab = sm + d * 32768 + mq * 8192;
#pragma unroll
    for (int i = 0; i < 4; ++i) {
      int rh = wm * 64 + i * 16 + ln15;
#pragma unroll
      for (int ks = 0; ks < 2; ++ks)
        af[i * 2 + ks] = *(const h8*)&Ab[rh * 64 + (((ks * 4 + lq)) ^ (rh & 7)) * 8];
    }
  };
  auto readB = [&](int d, int nq, h8* bf) {   // 4 x ds_read_b128
    const _Float16* Bb = sm + d * 32768 + 16384 + nq * 8192;
#pragma unroll
    for (int j = 0; j < 2; ++j) {
      int rh = wn * 32 + j * 16 + ln15;
#pragma unroll
      for (int ks = 0; ks < 2; ++ks)
        bf[j * 2 + ks] = *(const h8*)&Bb[rh * 64 + (((ks * 4 + lq)) ^ (rh & 7)) * 8];
    }
  };
  auto mfmaQ = [&](int mq, int nq, const h8* bf) {  // 16 MFMA = one C-quadrant
    __builtin_amdgcn_s_setprio(1);
#pragma unroll
    for (int ks = 0; ks < 2; ++ks)
#pragma unroll
      for (int i = 0; i < 4; ++i)
#pragma unroll
        for (int j = 0; j < 2; ++j)
          acc[mq][i][nq][j] = __builtin_amdgcn_mfma_f32_16x16x32_f16(
              af[i * 2 + ks], bf[j * 2 + ks], acc[mq][i][nq][j], 0, 0, 0);
    __builtin_amdgcn_s_setprio(0);
  };

  constexpr int KSTEPS = KD / 64;      // 16 (G1) or 64 (G2)

  // ---- prologue ----
  loadB(0);                                          // 8 vmem
  stageA(0, 0); stageA(0, 1); stageA(1, 0); stageA(1, 1);   // 8 vmem
  asm volatile("s_waitcnt vmcnt(8)" ::: "memory");   // B(0) returned (A x8 newer)
  writeB(0);                                         // -> Bs[0]
  loadB(1);                                          // 8 vmem (reg set free)
  asm volatile("s_waitcnt vmcnt(12)" ::: "memory");  // A(0) done (A(1)x4+B(1)x8 newer)
  asm volatile("s_waitcnt lgkmcnt(0)" ::: "memory"); // writeB(0) drained
  __builtin_amdgcn_s_barrier();

#pragma unroll 2
  for (int t = 0; t < KSTEPS; ++t) {
    int d = t & 1;
    // P1: quadrant (mq0,nq0)
    readA(d, 0);
    readB(d, 0, bf0);
    __builtin_amdgcn_s_barrier();
    asm volatile("s_waitcnt lgkmcnt(0)" ::: "memory");
    mfmaQ(0, 0, bf0);
    __builtin_amdgcn_s_barrier();
    // P2: (mq0,nq1); A0[d] retired at P1 -> stage A(t+2) half0 in place
    readB(d, 1, bf1);
    if (t + 2 < KSTEPS) stageA(t + 2, 0);
    __builtin_amdgcn_s_barrier();
    asm volatile("s_waitcnt lgkmcnt(0)" ::: "memory");
    mfmaQ(0, 1, bf1);
    __builtin_amdgcn_s_barrier();
    // P3: (mq1,nq1)
    readA(d, 1);
    __builtin_amdgcn_s_barrier();
    asm volatile("s_waitcnt lgkmcnt(0)" ::: "memory");
    mfmaQ(1, 1, bf1);
    __builtin_amdgcn_s_barrier();
    // P4: (mq1,nq0); A1[d] retired at P3 -> stage A(t+2) half1;
    //     counted wait, commit B(t+1) to LDS, issue B(t+2).
    if (t + 2 < KSTEPS) stageA(t + 2, 1);
    if (t + 1 < KSTEPS) {
      if (t + 2 < KSTEPS) asm volatile("s_waitcnt vmcnt(4)" ::: "memory");
      else                asm volatile("s_waitcnt vmcnt(0)" ::: "memory");
      writeB(t + 1);                                 // -> Bs[(t+1)&1]
      if (t + 2 < KSTEPS) loadB(t + 2);
      asm volatile("s_waitcnt lgkmcnt(0)" ::: "memory");
    }
    __builtin_amdgcn_s_barrier();
    mfmaQ(1, 0, bf0);
    __builtin_amdgcn_s_barrier();
  }

  // ---- epilogue ----
  float bj[2][2];
#pragma unroll
  for (int nq = 0; nq < 2; ++nq)
#pragma unroll
    for (int j = 0; j < 2; ++j)
      bj[nq][j] = bias[e * ND + n0 + nq * 128 + wn * 32 + j * 16 + ln15];

  if (G1) {
    // LDS-bounce (reuse sm): two 128-row halves, [128][264] fp16 padded
    _Float16* cs = sm;
#pragma unroll
    for (int mq = 0; mq < 2; ++mq) {
      if (mq) __syncthreads();
#pragma unroll
      for (int i = 0; i < 4; ++i)
#pragma unroll
        for (int reg = 0; reg < 4; ++reg) {
          int row = wm * 64 + i * 16 + lq * 4 + reg;
#pragma unroll
          for (int nq = 0; nq < 2; ++nq)
#pragma unroll
            for (int j = 0; j < 2; ++j)
              cs[row * 264 + nq * 128 + wn * 32 + j * 16 + ln15] =
                  (_Float16)fmaxf(acc[mq][i][nq][j][reg] + bj[nq][j], 0.f);
        }
      __syncthreads();
#pragma unroll
      for (int p = 0; p < 8; ++p) {
        int idx = p * 512 + tid;          // 128 rows x 32 h8-chunks
        int row = idx >> 5, ch = idx & 31;
        *(h8*)(Hout + (long)(p0 + mq * 128 + row) * DHID + n0 + ch * 8) =
            *(const h8*)&cs[row * 264 + ch * 8];
      }
    }
  } else {
#pragma unroll
    for (int mq = 0; mq < 2; ++mq)
#pragma unroll
      for (int i = 0; i < 4; ++i)
#pragma unroll
        for (int reg = 0; reg < 4; ++reg) {
          int p = p0 + mq * 128 + wm * 64 + i * 16 + lq * 4 + reg;
          float wgt = pw[p];
          if (wgt != 0.f) {
            int tk = ptok[p];
            float* orow = out + (long)tk * DOUT + n0;
#pragma unroll
            for (int nq = 0; nq < 2; ++nq)
#pragma unroll
              for (int j = 0; j < 2; ++j)
                atomicAdd(&orow[nq * 128 + wn * 32 + j * 16 + ln15],
                          wgt * (acc[mq][i][nq][j][reg] + bj[nq][j]));
          }
        }
  }
}

extern "C" void kernel_launch(void* const* d_in, const int* in_sizes, int n_in,
                              void* d_out, int out_size, void* d_ws, size_t ws_size,
                              hipStream_t stream) {
  const float* x  = (const float*)d_in[0];
  const float* Wg = (const float*)d_in[1];
  const float* W1 = (const float*)d_in[2];
  const float* b1 = (const float*)d_in[3];
  const float* W2 = (const float*)d_in[4];
  const float* b2 = (const float*)d_in[5];
  float* out = (float*)d_out;
  char* ws = (char*)d_ws;

  size_t H_OFF  = 0;                                        // 167,772,160
  size_t X_OFF  = H_OFF  + (size_t)PADMAX * DHID * 2;
  size_t TE_OFF = X_OFF  + (size_t)NTOK * DIN * 2;
  size_t TW_OFF = TE_OFF + (size_t)NPAIR * 4;
  size_t PT_OFF = TW_OFF + (size_t)NPAIR * 4;
  size_t PW_OFF = PT_OFF + (size_t)PADMAX * 4;
  size_t CT_OFF = PW_OFF + (size_t)PADMAX * 4;
  size_t END    = CT_OFF + 4096;
  if (ws_size < END) {
    fprintf(stderr, "kernel_launch: ws too small (%zu < %zu)\n", ws_size, END);
    return;
  }
  _Float16* H   = (_Float16*)(ws + H_OFF);
  _Float16* x16 = (_Float16*)(ws + X_OFF);
  int*   te   = (int*)(ws + TE_OFF);
  float* tw   = (float*)(ws + TW_OFF);
  int*   pt   = (int*)(ws + PT_OFF);
  float* pw   = (float*)(ws + PW_OFF);
  int*   ctrl = (int*)(ws + CT_OFF);

  k_init<<<NTOK * DIN / (256 * 4), 256, 0, stream>>>(out, x, x16, pt, pw, ctrl);
  k_gate<<<NTOK / 4, 256, 0, stream>>>(x, Wg, te, tw, ctrl);
  k_scan<<<1, 256, 0, stream>>>(ctrl);
  k_assign<<<NTOK / 256, 256, 0, stream>>>(te, tw, ctrl, pt, pw);

  // G1: x16[tok][1024] x W1[e][1024][4096] -> H fp16 (+b1, relu). 1280 works.
  k_gemm<DIN, DHID, 1><<<dim3((DHID / 256) * MAXTILES), 512, 0, stream>>>(
      x16, W1, b1, ctrl, pt, pw, H, nullptr);

  // G2: H[p][4096] x W2[e][4096][1024] -> out atomics (+b2, gate weights). 320 works.
  k_gemm<DHID, DOUT, 0><<<dim3((DOUT / 256) * MAXTILES), 512, 0, stream>>>(
      H, W2, b2, ctrl, pt, pw, nullptr, out);
}

// Round 6
// 1774.402 us; speedup vs baseline: 1.0541x; 1.0541x over previous
//
#include <hip/hip_runtime.h>
#include <cstdio>

#define DIN   1024
#define DHID  4096
#define DOUT  1024
#define NEXP  16
#define NTOK  8192
#define NPAIR (NTOK * 2)
#define PADMAX 20480          // 16384 + 16*255 rounded up to 256
#define MAXTILES 80           // max sum of per-expert ceil(cnt/256)

typedef _Float16 h8 __attribute__((ext_vector_type(8)));
typedef _Float16 h4 __attribute__((ext_vector_type(4)));
typedef float    f4 __attribute__((ext_vector_type(4)));

// ctrl[] int indices
#define C_CNT  0    // [16] per-expert pair counts
#define C_POFF 16   // [16] padded segment offsets
#define C_CUR  32   // [16] assignment cursors
#define C_NT   48   // total tiles
#define C_TE   64   // [80] tile -> expert
#define C_TP   256  // [80] tile -> p0 (padded row start)

__device__ __forceinline__ void async16(const void* g, void* l) {
  __builtin_amdgcn_global_load_lds((const __attribute__((address_space(1))) void*)g,
                                   (__attribute__((address_space(3))) void*)l, 16, 0, 0);
}

// ---- init: zero out, convert x->fp16, default perm, zero ctrl ----
__global__ void k_init(float* __restrict__ out, const float* __restrict__ x,
                       _Float16* __restrict__ x16, int* __restrict__ ptok,
                       float* __restrict__ pw, int* __restrict__ ctrl) {
  int i = blockIdx.x * 256 + threadIdx.x;           // 2,097,152 threads
  ((f4*)out)[i] = (f4){0.f, 0.f, 0.f, 0.f};
  float4 v = ((const float4*)x)[i];
  h4 hv = {(_Float16)v.x, (_Float16)v.y, (_Float16)v.z, (_Float16)v.w};
  ((h4*)x16)[i] = hv;
  if (i < PADMAX) { ptok[i] = 0; pw[i] = 0.f; }
  if (i < 1024) ctrl[i] = 0;
}

// ---- gating: logits, top-2, softmax weights, counts. 1 wave/token ----
__global__ void k_gate(const float* __restrict__ x, const float* __restrict__ wg,
                       int* __restrict__ te, float* __restrict__ tw,
                       int* __restrict__ ctrl) {
  int t = blockIdx.x * 4 + (threadIdx.x >> 6);
  int l = threadIdx.x & 63;
  const float* xr = x + (long)t * DIN;
  float acc[NEXP];
#pragma unroll
  for (int e = 0; e < NEXP; ++e) acc[e] = 0.f;
  for (int k = l; k < DIN; k += 64) {
    float xv = xr[k];
    const float4* wr = (const float4*)(wg + (long)k * NEXP);
    float4 a = wr[0], b = wr[1], c = wr[2], d = wr[3];
    acc[0]  += xv * a.x; acc[1]  += xv * a.y; acc[2]  += xv * a.z; acc[3]  += xv * a.w;
    acc[4]  += xv * b.x; acc[5]  += xv * b.y; acc[6]  += xv * b.z; acc[7]  += xv * b.w;
    acc[8]  += xv * c.x; acc[9]  += xv * c.y; acc[10] += xv * c.z; acc[11] += xv * c.w;
    acc[12] += xv * d.x; acc[13] += xv * d.y; acc[14] += xv * d.z; acc[15] += xv * d.w;
  }
#pragma unroll
  for (int off = 32; off > 0; off >>= 1) {
#pragma unroll
    for (int e = 0; e < NEXP; ++e) acc[e] += __shfl_xor(acc[e], off, 64);
  }
  if (l == 0) {
    float v0 = -1e30f; int e0 = 0;
#pragma unroll
    for (int e = 0; e < NEXP; ++e) if (acc[e] > v0) { v0 = acc[e]; e0 = e; }
    float v1 = -1e30f; int e1 = 0;
#pragma unroll
    for (int e = 0; e < NEXP; ++e) if (e != e0 && acc[e] > v1) { v1 = acc[e]; e1 = e; }
    float d = expf(v1 - v0);
    float den = 1.f / (1.f + d);
    te[2 * t] = e0;     tw[2 * t] = den;       // w0 (top-1)
    te[2 * t + 1] = e1; tw[2 * t + 1] = d * den;
    atomicAdd(&ctrl[C_CNT + e0], 1);
    atomicAdd(&ctrl[C_CNT + e1], 1);
  }
}

// ---- scan: padded offsets (256-granular), cursors, tile table ----
__global__ void k_scan(int* __restrict__ ctrl) {
  __shared__ int sOff[NEXP], sT0[NEXP], sTiles[NEXP];
  int tid = threadIdx.x;
  if (tid == 0) {
    int off = 0, nt = 0;
    for (int e = 0; e < NEXP; ++e) {
      int c = ctrl[C_CNT + e];
      int tiles = (c + 255) >> 8;
      ctrl[C_POFF + e] = off;
      ctrl[C_CUR + e] = off;
      sOff[e] = off; sT0[e] = nt; sTiles[e] = tiles;
      nt += tiles;
      off += tiles * 256;
    }
    ctrl[C_NT] = nt;
  }
  __syncthreads();
  int nt = sT0[NEXP - 1] + sTiles[NEXP - 1];
  for (int j = tid; j < nt; j += blockDim.x) {
    int e = 0;
#pragma unroll
    for (int k = 1; k < NEXP; ++k) if (j >= sT0[k]) e = k;
    ctrl[C_TE + j] = e;
    ctrl[C_TP + j] = sOff[e] + (j - sT0[e]) * 256;
  }
}

// ---- assign: fill permuted pair arrays ----
__global__ void k_assign(const int* __restrict__ te, const float* __restrict__ tw,
                         int* __restrict__ ctrl, int* __restrict__ ptok,
                         float* __restrict__ pw) {
  int t = blockIdx.x * 256 + threadIdx.x;
#pragma unroll
  for (int s = 0; s < 2; ++s) {
    int e = te[2 * t + s];
    int pos = atomicAdd(&ctrl[C_CUR + e], 1);
    ptok[pos] = t;
    pw[pos] = tw[2 * t + s];
  }
}

// ---- grouped GEMM: 256x256 tile, BK=64, 8 waves (2Mx4N), 8-phase schedule ----
// Fused B: staged directly from native W[e][k][n] fp32 (no pre-transpose pass).
//   A: global_load_lds fp16, 2 tiles ahead, in-place dbuf juggling (old hash).
//   B (v2, conflict-free): wave w owns k-octet w. Lane l loads 8x float4 from
//     rows t*64+w*8+i, cols n0+4l (1024B coalesced/row); in-register transpose
//     -> 4x ds_write_b128, one per column c4. B hash (write AND read):
//       chunk(kq, r) = kq ^ (r&7) ^ ((r>>3)&7)
//     -> per instr each chunk gets exactly 8 lanes = b128 structural floor.
//   Counted waits: P4 steady vmcnt(8) (drains exactly B(t+1); A(t+2) stays in
//   flight), prologue vmcnt(16), tail vmcnt(0).
// 1D grid, bijective XCD chunk swizzle, mt-fastest (L2 B-slice sharing).
template<int KD, int ND, int G1>
__global__ __launch_bounds__(512, 2)
void k_gemm(const _Float16* __restrict__ A, const float* __restrict__ W,
            const float* __restrict__ bias, const int* __restrict__ ctrl,
            const int* __restrict__ ptok, const float* __restrict__ pw,
            _Float16* __restrict__ Hout, float* __restrict__ out) {
  __shared__ __align__(16) _Float16 sm[65536];   // 128 KB

  constexpr int NWK = (ND / 256) * MAXTILES;
  constexpr int QX = NWK / 8;                    // chunk per XCD
  int bid = blockIdx.x;
  int wid = (bid & 7) * QX + (bid >> 3);         // bijective XCD chunk swizzle
  int mt = wid % MAXTILES;
  int nb = wid / MAXTILES;

  if (mt >= ctrl[C_NT]) return;
  int e  = ctrl[C_TE + mt];
  int p0 = ctrl[C_TP + mt];
  int n0 = nb * 256;
  int tid = threadIdx.x;
  int w = tid >> 6, l = tid & 63;
  int wm = w & 1, wn = w >> 1;           // 2 M-warps x 4 N-warps
  int ln15 = l & 15, lq = l >> 4;

  // ---- A staging pointers (async16): halves h=0,1, slots j=0,1 ----
  const _Float16* agp[4];
#pragma unroll
  for (int h = 0; h < 2; ++h)
#pragma unroll
    for (int j = 0; j < 2; ++j) {
      int r = (w * 2 + j) * 8 + (l >> 3);          // row in half, 0..127
      int c = (l & 7) ^ (r & 7);                   // A swizzle-on-source
      long arow = G1 ? (long)ptok[p0 + h * 128 + r] : (long)(p0 + h * 128 + r);
      agp[h * 2 + j] = A + arow * KD + c * 8;
    }
  auto stageA = [&](int t, int h) {
    _Float16* dst = sm + (t & 1) * 32768 + h * 8192 + w * 1024;
    long koff = (long)t * 64;
    async16(agp[h * 2 + 0] + koff, dst);
    async16(agp[h * 2 + 1] + koff, dst + 512);
  };

  // ---- B reg-staging: wave w = k-octet w; lane l = cols 4l..4l+3 ----
  const float* gBW = W + ((long)e * KD + w * 8) * ND + n0 + l * 4;
  int bwo[4];                            // LDS elem offsets per c4 (sans dbuf)
#pragma unroll
  for (int c4 = 0; c4 < 4; ++c4) {
    int r = l * 4 + c4;                  // 0..255
    bwo[c4] = 16384 + (r >> 7) * 8192 + (r & 127) * 64
            + ((w ^ (r & 7) ^ ((r >> 3) & 7)) << 3);
  }
  f4 breg[8];
  auto loadB = [&](int t) {
    const float* p = gBW + (long)t * 64 * ND;
#pragma unroll
    for (int i = 0; i < 8; ++i) breg[i] = *(const f4*)(p + (long)i * ND);
  };
  auto writeB = [&](int t) {             // in-register 8x4 transpose -> b128 x4
    _Float16* dstb = sm + (t & 1) * 32768;
#pragma unroll
    for (int c4 = 0; c4 < 4; ++c4) {
      h8 hv = {(_Float16)breg[0][c4], (_Float16)breg[1][c4],
               (_Float16)breg[2][c4], (_Float16)breg[3][c4],
               (_Float16)breg[4][c4], (_Float16)breg[5][c4],
               (_Float16)breg[6][c4], (_Float16)breg[7][c4]};
      *(h8*)&dstb[bwo[c4]] = hv;
    }
  };

  f4 acc[2][4][2][2];
#pragma unroll
  for (int mq = 0; mq < 2; ++mq)
#pragma unroll
    for (int i = 0; i < 4; ++i)
#pragma unroll
      for (int nq = 0; nq < 2; ++nq)
#pragma unroll
        for (int j = 0; j < 2; ++j) acc[mq][i][nq][j] = (f4){0.f, 0.f, 0.f, 0.f};

  h8 af[8], bf0[4], bf1[4];

  auto readA = [&](int d, int mq) {     // 8 x ds_read_b128 (old A hash)
    const _Float16* Ab = sm + d * 32768 + mq * 8192;
#pragma unroll
    for (int i = 0; i < 4; ++i) {
      int rh = wm * 64 + i * 16 + ln15;
#pragma unroll
      for (int ks = 0; ks < 2; ++ks)
        af[i * 2 + ks] = *(const h8*)&Ab[rh * 64 + (((ks * 4 + lq)) ^ (rh & 7)) * 8];
    }
  };
  auto readB = [&](int d, int nq, h8* bf) {   // 4 x ds_read_b128 (new B hash)
    const _Float16* Bb = sm + d * 32768 + 16384 + nq * 8192;
#pragma unroll
    for (int j = 0; j < 2; ++j) {
      int rh = wn * 32 + j * 16 + ln15;
#pragma unroll
      for (int ks = 0; ks < 2; ++ks)
        bf[j * 2 + ks] = *(const h8*)
            &Bb[(rh & 127) * 64 + (((ks * 4 + lq)) ^ (rh & 7) ^ ((rh >> 3) & 7)) * 8];
    }
  };
  auto mfmaQ = [&](int mq, int nq, const h8* bf) {  // 16 MFMA = one C-quadrant
    __builtin_amdgcn_s_setprio(1);
#pragma unroll
    for (int ks = 0; ks < 2; ++ks)
#pragma unroll
      for (int i = 0; i < 4; ++i)
#pragma unroll
        for (int j = 0; j < 2; ++j)
          acc[mq][i][nq][j] = __builtin_amdgcn_mfma_f32_16x16x32_f16(
              af[i * 2 + ks], bf[j * 2 + ks], acc[mq][i][nq][j], 0, 0, 0);
    __builtin_amdgcn_s_setprio(0);
  };

  constexpr int KSTEPS = KD / 64;      // 16 (G1) or 64 (G2)

  // ---- prologue ----
  loadB(0);                                          // 8 vmem
  stageA(0, 0); stageA(0, 1); stageA(1, 0); stageA(1, 1);   // 16 vmem
  asm volatile("s_waitcnt vmcnt(16)" ::: "memory");  // B(0) returned
  writeB(0);                                         // -> Bs[0]
  loadB(1);                                          // 8 vmem
  asm volatile("s_waitcnt vmcnt(16)" ::: "memory");  // A(0) done (A(1)8+B(1)8 fly)
  asm volatile("s_waitcnt lgkmcnt(0)" ::: "memory"); // writeB(0) drained
  __builtin_amdgcn_s_barrier();

#pragma unroll 2
  for (int t = 0; t < KSTEPS; ++t) {
    int d = t & 1;
    // P1: quadrant (mq0,nq0)
    readA(d, 0);
    readB(d, 0, bf0);
    __builtin_amdgcn_s_barrier();
    asm volatile("s_waitcnt lgkmcnt(0)" ::: "memory");
    mfmaQ(0, 0, bf0);
    __builtin_amdgcn_s_barrier();
    // P2: (mq0,nq1); A0[d] retired at P1 -> stage A(t+2) half0 in place
    readB(d, 1, bf1);
    if (t + 2 < KSTEPS) stageA(t + 2, 0);
    __builtin_amdgcn_s_barrier();
    asm volatile("s_waitcnt lgkmcnt(0)" ::: "memory");
    mfmaQ(0, 1, bf1);
    __builtin_amdgcn_s_barrier();
    // P3: (mq1,nq1)
    readA(d, 1);
    __builtin_amdgcn_s_barrier();
    asm volatile("s_waitcnt lgkmcnt(0)" ::: "memory");
    mfmaQ(1, 1, bf1);
    __builtin_amdgcn_s_barrier();
    // P4: (mq1,nq0); A1[d] retired at P3 -> stage A(t+2) half1;
    //     counted wait (drains exactly B(t+1)), commit B(t+1), issue B(t+2).
    if (t + 2 < KSTEPS) stageA(t + 2, 1);
    if (t + 1 < KSTEPS) {
      if (t + 2 < KSTEPS) asm volatile("s_waitcnt vmcnt(8)" ::: "memory");
      else                asm volatile("s_waitcnt vmcnt(0)" ::: "memory");
      writeB(t + 1);                                 // -> Bs[(t+1)&1]
      if (t + 2 < KSTEPS) loadB(t + 2);
      asm volatile("s_waitcnt lgkmcnt(0)" ::: "memory");
    }
    __builtin_amdgcn_s_barrier();
    mfmaQ(1, 0, bf0);
    __builtin_amdgcn_s_barrier();
  }

  // ---- epilogue ----
  float bj[2][2];
#pragma unroll
  for (int nq = 0; nq < 2; ++nq)
#pragma unroll
    for (int j = 0; j < 2; ++j)
      bj[nq][j] = bias[e * ND + n0 + nq * 128 + wn * 32 + j * 16 + ln15];

  if (G1) {
    // LDS-bounce (reuse sm): two 128-row halves, [128][264] fp16 padded
    _Float16* cs = sm;
#pragma unroll
    for (int mq = 0; mq < 2; ++mq) {
      if (mq) __syncthreads();
#pragma unroll
      for (int i = 0; i < 4; ++i)
#pragma unroll
        for (int reg = 0; reg < 4; ++reg) {
          int row = wm * 64 + i * 16 + lq * 4 + reg;
#pragma unroll
          for (int nq = 0; nq < 2; ++nq)
#pragma unroll
            for (int j = 0; j < 2; ++j)
              cs[row * 264 + nq * 128 + wn * 32 + j * 16 + ln15] =
                  (_Float16)fmaxf(acc[mq][i][nq][j][reg] + bj[nq][j], 0.f);
        }
      __syncthreads();
#pragma unroll
      for (int p = 0; p < 8; ++p) {
        int idx = p * 512 + tid;          // 128 rows x 32 h8-chunks
        int row = idx >> 5, ch = idx & 31;
        *(h8*)(Hout + (long)(p0 + mq * 128 + row) * DHID + n0 + ch * 8) =
            *(const h8*)&cs[row * 264 + ch * 8];
      }
    }
  } else {
#pragma unroll
    for (int mq = 0; mq < 2; ++mq)
#pragma unroll
      for (int i = 0; i < 4; ++i)
#pragma unroll
        for (int reg = 0; reg < 4; ++reg) {
          int p = p0 + mq * 128 + wm * 64 + i * 16 + lq * 4 + reg;
          float wgt = pw[p];
          if (wgt != 0.f) {
            int tk = ptok[p];
            float* orow = out + (long)tk * DOUT + n0;
#pragma unroll
            for (int nq = 0; nq < 2; ++nq)
#pragma unroll
              for (int j = 0; j < 2; ++j)
                atomicAdd(&orow[nq * 128 + wn * 32 + j * 16 + ln15],
                          wgt * (acc[mq][i][nq][j][reg] + bj[nq][j]));
          }
        }
  }
}

extern "C" void kernel_launch(void* const* d_in, const int* in_sizes, int n_in,
                              void* d_out, int out_size, void* d_ws, size_t ws_size,
                              hipStream_t stream) {
  const float* x  = (const float*)d_in[0];
  const float* Wg = (const float*)d_in[1];
  const float* W1 = (const float*)d_in[2];
  const float* b1 = (const float*)d_in[3];
  const float* W2 = (const float*)d_in[4];
  const float* b2 = (const float*)d_in[5];
  float* out = (float*)d_out;
  char* ws = (char*)d_ws;

  size_t H_OFF  = 0;                                        // 167,772,160
  size_t X_OFF  = H_OFF  + (size_t)PADMAX * DHID * 2;
  size_t TE_OFF = X_OFF  + (size_t)NTOK * DIN * 2;
  size_t TW_OFF = TE_OFF + (size_t)NPAIR * 4;
  size_t PT_OFF = TW_OFF + (size_t)NPAIR * 4;
  size_t PW_OFF = PT_OFF + (size_t)PADMAX * 4;
  size_t CT_OFF = PW_OFF + (size_t)PADMAX * 4;
  size_t END    = CT_OFF + 4096;
  if (ws_size < END) {
    fprintf(stderr, "kernel_launch: ws too small (%zu < %zu)\n", ws_size, END);
    return;
  }
  _Float16* H   = (_Float16*)(ws + H_OFF);
  _Float16* x16 = (_Float16*)(ws + X_OFF);
  int*   te   = (int*)(ws + TE_OFF);
  float* tw   = (float*)(ws + TW_OFF);
  int*   pt   = (int*)(ws + PT_OFF);
  float* pw   = (float*)(ws + PW_OFF);
  int*   ctrl = (int*)(ws + CT_OFF);

  k_init<<<NTOK * DIN / (256 * 4), 256, 0, stream>>>(out, x, x16, pt, pw, ctrl);
  k_gate<<<NTOK / 4, 256, 0, stream>>>(x, Wg, te, tw, ctrl);
  k_scan<<<1, 256, 0, stream>>>(ctrl);
  k_assign<<<NTOK / 256, 256, 0, stream>>>(te, tw, ctrl, pt, pw);

  // G1: x16[tok][1024] x W1[e][1024][4096] -> H fp16 (+b1, relu). 1280 works.
  k_gemm<DIN, DHID, 1><<<dim3((DHID / 256) * MAXTILES), 512, 0, stream>>>(
      x16, W1, b1, ctrl, pt, pw, H, nullptr);

  // G2: H[p][4096] x W2[e][4096][1024] -> out atomics (+b2, gate weights). 320 works.
  k_gemm<DHID, DOUT, 0><<<dim3((DOUT / 256) * MAXTILES), 512, 0, stream>>>(
      H, W2, b2, ctrl, pt, pw, nullptr, out);
}

// Round 7
// 1265.683 us; speedup vs baseline: 1.4777x; 1.4019x over previous
//
#include <hip/hip_runtime.h>
#include <cstdio>

#define DIN   1024
#define DHID  4096
#define DOUT  1024
#define NEXP  16
#define NTOK  8192
#define NPAIR (NTOK * 2)
#define PADMAX 20480          // 16384 + 16*255 rounded up to 256
#define MAXTILES 80           // max sum of per-expert ceil(cnt/256)

typedef _Float16 h8 __attribute__((ext_vector_type(8)));
typedef _Float16 h4 __attribute__((ext_vector_type(4)));
typedef float    f4 __attribute__((ext_vector_type(4)));

// ctrl[] int indices
#define C_CNT  0    // [16] per-expert pair counts
#define C_POFF 16   // [16] padded segment offsets
#define C_CUR  32   // [16] assignment cursors
#define C_NT   48   // total tiles
#define C_TE   64   // [80] tile -> expert
#define C_TP   256  // [80] tile -> p0 (padded row start)

__device__ __forceinline__ void async16(const void* g, void* l) {
  __builtin_amdgcn_global_load_lds((const __attribute__((address_space(1))) void*)g,
                                   (__attribute__((address_space(3))) void*)l, 16, 0, 0);
}

// ---- init: zero out, convert x->fp16, default perm, zero ctrl ----
__global__ void k_init(float* __restrict__ out, const float* __restrict__ x,
                       _Float16* __restrict__ x16, int* __restrict__ ptok,
                       float* __restrict__ pw, int* __restrict__ ctrl) {
  int i = blockIdx.x * 256 + threadIdx.x;           // 2,097,152 threads
  ((f4*)out)[i] = (f4){0.f, 0.f, 0.f, 0.f};
  float4 v = ((const float4*)x)[i];
  h4 hv = {(_Float16)v.x, (_Float16)v.y, (_Float16)v.z, (_Float16)v.w};
  ((h4*)x16)[i] = hv;
  if (i < PADMAX) { ptok[i] = 0; pw[i] = 0.f; }
  if (i < 1024) ctrl[i] = 0;
}

// ---- gating: logits, top-2, softmax weights, counts. 1 wave/token ----
__global__ void k_gate(const float* __restrict__ x, const float* __restrict__ wg,
                       int* __restrict__ te, float* __restrict__ tw,
                       int* __restrict__ ctrl) {
  int t = blockIdx.x * 4 + (threadIdx.x >> 6);
  int l = threadIdx.x & 63;
  const float* xr = x + (long)t * DIN;
  float acc[NEXP];
#pragma unroll
  for (int e = 0; e < NEXP; ++e) acc[e] = 0.f;
  for (int k = l; k < DIN; k += 64) {
    float xv = xr[k];
    const float4* wr = (const float4*)(wg + (long)k * NEXP);
    float4 a = wr[0], b = wr[1], c = wr[2], d = wr[3];
    acc[0]  += xv * a.x; acc[1]  += xv * a.y; acc[2]  += xv * a.z; acc[3]  += xv * a.w;
    acc[4]  += xv * b.x; acc[5]  += xv * b.y; acc[6]  += xv * b.z; acc[7]  += xv * b.w;
    acc[8]  += xv * c.x; acc[9]  += xv * c.y; acc[10] += xv * c.z; acc[11] += xv * c.w;
    acc[12] += xv * d.x; acc[13] += xv * d.y; acc[14] += xv * d.z; acc[15] += xv * d.w;
  }
#pragma unroll
  for (int off = 32; off > 0; off >>= 1) {
#pragma unroll
    for (int e = 0; e < NEXP; ++e) acc[e] += __shfl_xor(acc[e], off, 64);
  }
  if (l == 0) {
    float v0 = -1e30f; int e0 = 0;
#pragma unroll
    for (int e = 0; e < NEXP; ++e) if (acc[e] > v0) { v0 = acc[e]; e0 = e; }
    float v1 = -1e30f; int e1 = 0;
#pragma unroll
    for (int e = 0; e < NEXP; ++e) if (e != e0 && acc[e] > v1) { v1 = acc[e]; e1 = e; }
    float d = expf(v1 - v0);
    float den = 1.f / (1.f + d);
    te[2 * t] = e0;     tw[2 * t] = den;       // w0 (top-1)
    te[2 * t + 1] = e1; tw[2 * t + 1] = d * den;
    atomicAdd(&ctrl[C_CNT + e0], 1);
    atomicAdd(&ctrl[C_CNT + e1], 1);
  }
}

// ---- scan: padded offsets (256-granular), cursors, tile table ----
__global__ void k_scan(int* __restrict__ ctrl) {
  __shared__ int sOff[NEXP], sT0[NEXP], sTiles[NEXP];
  int tid = threadIdx.x;
  if (tid == 0) {
    int off = 0, nt = 0;
    for (int e = 0; e < NEXP; ++e) {
      int c = ctrl[C_CNT + e];
      int tiles = (c + 255) >> 8;
      ctrl[C_POFF + e] = off;
      ctrl[C_CUR + e] = off;
      sOff[e] = off; sT0[e] = nt; sTiles[e] = tiles;
      nt += tiles;
      off += tiles * 256;
    }
    ctrl[C_NT] = nt;
  }
  __syncthreads();
  int nt = sT0[NEXP - 1] + sTiles[NEXP - 1];
  for (int j = tid; j < nt; j += blockDim.x) {
    int e = 0;
#pragma unroll
    for (int k = 1; k < NEXP; ++k) if (j >= sT0[k]) e = k;
    ctrl[C_TE + j] = e;
    ctrl[C_TP + j] = sOff[e] + (j - sT0[e]) * 256;
  }
}

// ---- assign: fill permuted pair arrays ----
__global__ void k_assign(const int* __restrict__ te, const float* __restrict__ tw,
                         int* __restrict__ ctrl, int* __restrict__ ptok,
                         float* __restrict__ pw) {
  int t = blockIdx.x * 256 + threadIdx.x;
#pragma unroll
  for (int s = 0; s < 2; ++s) {
    int e = te[2 * t + s];
    int pos = atomicAdd(&ctrl[C_CUR + e], 1);
    ptok[pos] = t;
    pw[pos] = tw[2 * t + s];
  }
}

// ---- transpose+convert v2: W [E][R][C] fp32 -> out [E][C][R] fp16 ----
// 64c x 128r tile. In-register 4x4 transpose -> ds_write_b64 into 16B-chunk
// XOR-swizzled LDS (chunk = (r>>3)^(c&15)): conflict-free writes AND reads.
__global__ void k_transpose(const float* __restrict__ W, _Float16* __restrict__ out,
                            int R, int C) {
  __shared__ __align__(16) _Float16 lds[64 * 128];
  int e = blockIdx.z;
  const float* Wb = W + ((long)e * R + blockIdx.x * 128) * C + blockIdx.y * 64;
  _Float16* ob = out + ((long)e * C + blockIdx.y * 64) * R + blockIdx.x * 128;
  int tid = threadIdx.x;
  int l = tid & 63, w = tid >> 6;
  int c0 = (l & 15) * 4;
  int rq0 = (l >> 4) * 4 + w * 16;
#pragma unroll
  for (int rr = 0; rr < 2; ++rr) {
    int rq = rq0 + rr * 64;
    float4 v0 = *(const float4*)(Wb + (long)(rq + 0) * C + c0);
    float4 v1 = *(const float4*)(Wb + (long)(rq + 1) * C + c0);
    float4 v2 = *(const float4*)(Wb + (long)(rq + 2) * C + c0);
    float4 v3 = *(const float4*)(Wb + (long)(rq + 3) * C + c0);
    int rchunk = rq >> 3, rsub = rq & 7;
    {
      int c = c0 + 0;
      h4 hv = {(_Float16)v0.x, (_Float16)v1.x, (_Float16)v2.x, (_Float16)v3.x};
      *(h4*)&lds[c * 128 + ((rchunk ^ (c & 15)) << 3) + rsub] = hv;
    }
    {
      int c = c0 + 1;
      h4 hv = {(_Float16)v0.y, (_Float16)v1.y, (_Float16)v2.y, (_Float16)v3.y};
      *(h4*)&lds[c * 128 + ((rchunk ^ (c & 15)) << 3) + rsub] = hv;
    }
    {
      int c = c0 + 2;
      h4 hv = {(_Float16)v0.z, (_Float16)v1.z, (_Float16)v2.z, (_Float16)v3.z};
      *(h4*)&lds[c * 128 + ((rchunk ^ (c & 15)) << 3) + rsub] = hv;
    }
    {
      int c = c0 + 3;
      h4 hv = {(_Float16)v0.w, (_Float16)v1.w, (_Float16)v2.w, (_Float16)v3.w};
      *(h4*)&lds[c * 128 + ((rchunk ^ (c & 15)) << 3) + rsub] = hv;
    }
  }
  __syncthreads();
#pragma unroll
  for (int it = 0; it < 4; ++it) {
    int idx = it * 256 + tid;
    int c = idx >> 4, ch = idx & 15;
    h8 v = *(const h8*)&lds[c * 128 + ((ch ^ (c & 15)) << 3)];
    *(h8*)(ob + (long)c * R + ch * 8) = v;
  }
}

// ---- grouped GEMM: 256x256 tile, BK=64, 8 waves (2Mx4N), 8-phase schedule ----
// R4 base (proven 286us G2). ONE change: work order is now nb-FASTEST
// (wid = mt*NB + nb) so the NB blocks sharing one A-panel (H rows / x16 rows)
// are adjacent in wid-space -> same XCD chunk -> A re-reads served from that
// XCD's L2 instead of thrashing L3 (G2: H re-read 4x was the 1.7x over-fetch).
// T3+T4: counted vmcnt(6) once per K-tile; T5: setprio around MFMA clusters.
// LDS 128 KiB: 2 dbuf x {A,B} x 2 halves x 128x64 fp16. XOR swizzle on global
// source chunk (c ^= r&7); linear global_load_lds dest; same XOR on ds_read.
template<int KD, int ND, int G1>
__global__ __launch_bounds__(512, 2)
void k_gemm(const _Float16* __restrict__ A, const _Float16* __restrict__ Wt,
            const float* __restrict__ bias, const int* __restrict__ ctrl,
            const int* __restrict__ ptok, const float* __restrict__ pw,
            _Float16* __restrict__ Hout, float* __restrict__ out) {
  __shared__ __align__(16) _Float16 sm[65536];   // 128 KB

  constexpr int NB = ND / 256;
  constexpr int NW = NB * MAXTILES;
  constexpr int QX = NW / 8;                     // chunk per XCD
  int bid = blockIdx.x;
  int wid = (bid & 7) * QX + (bid >> 3);         // bijective XCD chunk swizzle
  int nb = wid % NB;                             // nb-FASTEST (A-panel locality)
  int mt = wid / NB;

  if (mt >= ctrl[C_NT]) return;
  int e  = ctrl[C_TE + mt];
  int p0 = ctrl[C_TP + mt];
  int n0 = nb * 256;
  int tid = threadIdx.x;
  int w = tid >> 6, l = tid & 63;
  int wm = w & 1, wn = w >> 1;           // 2 M-warps x 4 N-warps
  int ln15 = l & 15, lq = l >> 4;

  // ---- staging pointers: per (tensor, half, slot j) ----
  const _Float16* agp[4];   // [half*2+j]
  const _Float16* bgp[4];
#pragma unroll
  for (int h = 0; h < 2; ++h)
#pragma unroll
    for (int j = 0; j < 2; ++j) {
      int r = (w * 2 + j) * 8 + (l >> 3);          // row in half, 0..127
      int c = (l & 7) ^ (r & 7);
      long arow = G1 ? (long)ptok[p0 + h * 128 + r] : (long)(p0 + h * 128 + r);
      agp[h * 2 + j] = A + arow * KD + c * 8;
      bgp[h * 2 + j] = Wt + ((long)e * ND + n0 + h * 128 + r) * KD + c * 8;
    }

  // half ids: 0=A0 1=B0 2=A1 3=B1 (stage order within a tile)
  auto stageH = [&](int t, int half) {
    _Float16* dst = sm + (t & 1) * 32768 + (half & 1) * 16384 + (half >> 1) * 8192
                    + w * 1024;
    long koff = (long)t * 64;
    const _Float16* const* gp = (half & 1) ? bgp : agp;
#pragma unroll
    for (int j = 0; j < 2; ++j)
      async16(gp[(half >> 1) * 2 + j] + koff, dst + j * 512);
  };

  f4 acc[2][4][2][2];
#pragma unroll
  for (int mq = 0; mq < 2; ++mq)
#pragma unroll
    for (int i = 0; i < 4; ++i)
#pragma unroll
      for (int nq = 0; nq < 2; ++nq)
#pragma unroll
        for (int j = 0; j < 2; ++j) acc[mq][i][nq][j] = (f4){0.f, 0.f, 0.f, 0.f};

  h8 af[8], bf0[4], bf1[4];

  auto readA = [&](int d, int mq) {     // 8 x ds_read_b128
    const _Float16* Ab = sm + d * 32768 + mq * 8192;
#pragma unroll
    for (int i = 0; i < 4; ++i) {
      int rh = wm * 64 + i * 16 + ln15;
#pragma unroll
      for (int ks = 0; ks < 2; ++ks)
        af[i * 2 + ks] = *(const h8*)&Ab[rh * 64 + (((ks * 4 + lq)) ^ (rh & 7)) * 8];
    }
  };
  auto readB = [&](int d, int nq, h8* bf) {   // 4 x ds_read_b128
    const _Float16* Bb = sm + d * 32768 + 16384 + nq * 8192;
#pragma unroll
    for (int j = 0; j < 2; ++j) {
      int rh = wn * 32 + j * 16 + ln15;
#pragma unroll
      for (int ks = 0; ks < 2; ++ks)
        bf[j * 2 + ks] = *(const h8*)&Bb[rh * 64 + (((ks * 4 + lq)) ^ (rh & 7)) * 8];
    }
  };
  auto mfmaQ = [&](int mq, int nq, const h8* bf) {  // 16 MFMA = one C-quadrant
    __builtin_amdgcn_s_setprio(1);
#pragma unroll
    for (int ks = 0; ks < 2; ++ks)
#pragma unroll
      for (int i = 0; i < 4; ++i)
#pragma unroll
        for (int j = 0; j < 2; ++j)
          acc[mq][i][nq][j] = __builtin_amdgcn_mfma_f32_16x16x32_f16(
              af[i * 2 + ks], bf[j * 2 + ks], acc[mq][i][nq][j], 0, 0, 0);
    __builtin_amdgcn_s_setprio(0);
  };

  constexpr int KSTEPS = KD / 64;      // 16 (G1) or 64 (G2)

  // prologue: tile0 (4 halves) + tile1 (3 halves) = 14 loads/wave in flight
  stageH(0, 0); stageH(0, 1); stageH(0, 2); stageH(0, 3);
  stageH(1, 0); stageH(1, 1); stageH(1, 2);
  asm volatile("s_waitcnt vmcnt(6)" ::: "memory");   // tile0 landed, 3 halves in flight
  __builtin_amdgcn_s_barrier();

#pragma unroll 2
  for (int t = 0; t < KSTEPS; ++t) {
    int d = t & 1;
    // P1: quadrant (mq0,nq0) — needs A0,B0 (earliest staged)
    readA(d, 0);
    readB(d, 0, bf0);
    if (t + 1 < KSTEPS) stageH(t + 1, 3);            // B1 of next tile
    __builtin_amdgcn_s_barrier();
    asm volatile("s_waitcnt lgkmcnt(0)" ::: "memory");
    mfmaQ(0, 0, bf0);
    __builtin_amdgcn_s_barrier();
    // P2: (mq0,nq1) — needs B1; A0 retired -> stage t+2 A0 in place
    readB(d, 1, bf1);
    if (t + 2 < KSTEPS) stageH(t + 2, 0);
    __builtin_amdgcn_s_barrier();
    asm volatile("s_waitcnt lgkmcnt(0)" ::: "memory");
    mfmaQ(0, 1, bf1);
    __builtin_amdgcn_s_barrier();
    // P3: (mq1,nq1) — needs A1; B0 retired -> stage t+2 B0
    readA(d, 1);
    if (t + 2 < KSTEPS) stageH(t + 2, 1);
    __builtin_amdgcn_s_barrier();
    asm volatile("s_waitcnt lgkmcnt(0)" ::: "memory");
    mfmaQ(1, 1, bf1);
    __builtin_amdgcn_s_barrier();
    // P4: (mq1,nq0) — reuses af/bf0; A1 retired -> stage t+2 A1; counted wait
    if (t + 2 < KSTEPS) stageH(t + 2, 2);
    if (t + 1 < KSTEPS) {
      if (t + 2 < KSTEPS) asm volatile("s_waitcnt vmcnt(6)" ::: "memory");
      else                asm volatile("s_waitcnt vmcnt(0)" ::: "memory");
    }
    __builtin_amdgcn_s_barrier();
    mfmaQ(1, 0, bf0);
    __builtin_amdgcn_s_barrier();
  }

  // ---- epilogue ----
  float bj[2][2];
#pragma unroll
  for (int nq = 0; nq < 2; ++nq)
#pragma unroll
    for (int j = 0; j < 2; ++j)
      bj[nq][j] = bias[e * ND + n0 + nq * 128 + wn * 32 + j * 16 + ln15];

  if (G1) {
    // LDS-bounce (reuse sm): two 128-row halves, [128][264] fp16 padded
    _Float16* cs = sm;
#pragma unroll
    for (int mq = 0; mq < 2; ++mq) {
      if (mq) __syncthreads();
#pragma unroll
      for (int i = 0; i < 4; ++i)
#pragma unroll
        for (int reg = 0; reg < 4; ++reg) {
          int row = wm * 64 + i * 16 + lq * 4 + reg;
#pragma unroll
          for (int nq = 0; nq < 2; ++nq)
#pragma unroll
            for (int j = 0; j < 2; ++j)
              cs[row * 264 + nq * 128 + wn * 32 + j * 16 + ln15] =
                  (_Float16)fmaxf(acc[mq][i][nq][j][reg] + bj[nq][j], 0.f);
        }
      __syncthreads();
#pragma unroll
      for (int p = 0; p < 8; ++p) {
        int idx = p * 512 + tid;          // 128 rows x 32 h8-chunks
        int row = idx >> 5, ch = idx & 31;
        *(h8*)(Hout + (long)(p0 + mq * 128 + row) * DHID + n0 + ch * 8) =
            *(const h8*)&cs[row * 264 + ch * 8];
      }
    }
  } else {
#pragma unroll
    for (int mq = 0; mq < 2; ++mq)
#pragma unroll
      for (int i = 0; i < 4; ++i)
#pragma unroll
        for (int reg = 0; reg < 4; ++reg) {
          int p = p0 + mq * 128 + wm * 64 + i * 16 + lq * 4 + reg;
          float wgt = pw[p];
          if (wgt != 0.f) {
            int tk = ptok[p];
            float* orow = out + (long)tk * DOUT + n0;
#pragma unroll
            for (int nq = 0; nq < 2; ++nq)
#pragma unroll
              for (int j = 0; j < 2; ++j)
                atomicAdd(&orow[nq * 128 + wn * 32 + j * 16 + ln15],
                          wgt * (acc[mq][i][nq][j][reg] + bj[nq][j]));
          }
        }
  }
}

extern "C" void kernel_launch(void* const* d_in, const int* in_sizes, int n_in,
                              void* d_out, int out_size, void* d_ws, size_t ws_size,
                              hipStream_t stream) {
  const float* x  = (const float*)d_in[0];
  const float* Wg = (const float*)d_in[1];
  const float* W1 = (const float*)d_in[2];
  const float* b1 = (const float*)d_in[3];
  const float* W2 = (const float*)d_in[4];
  const float* b2 = (const float*)d_in[5];
  float* out = (float*)d_out;
  char* ws = (char*)d_ws;

  size_t WT_OFF = 0;                                   // fp16 W^T (reused W1 then W2)
  size_t H_OFF  = WT_OFF + (size_t)NEXP * DHID * DIN * 2;   // 134,217,728
  size_t X_OFF  = H_OFF  + (size_t)PADMAX * DHID * 2;       // +167,772,160
  size_t TE_OFF = X_OFF  + (size_t)NTOK * DIN * 2;          // +16,777,216
  size_t TW_OFF = TE_OFF + (size_t)NPAIR * 4;
  size_t PT_OFF = TW_OFF + (size_t)NPAIR * 4;
  size_t PW_OFF = PT_OFF + (size_t)PADMAX * 4;
  size_t CT_OFF = PW_OFF + (size_t)PADMAX * 4;
  size_t END    = CT_OFF + 4096;
  if (ws_size < END) {
    fprintf(stderr, "kernel_launch: ws too small (%zu < %zu)\n", ws_size, END);
    return;
  }
  _Float16* Wt  = (_Float16*)(ws + WT_OFF);
  _Float16* H   = (_Float16*)(ws + H_OFF);
  _Float16* x16 = (_Float16*)(ws + X_OFF);
  int*   te   = (int*)(ws + TE_OFF);
  float* tw   = (float*)(ws + TW_OFF);
  int*   pt   = (int*)(ws + PT_OFF);
  float* pw   = (float*)(ws + PW_OFF);
  int*   ctrl = (int*)(ws + CT_OFF);

  k_init<<<NTOK * DIN / (256 * 4), 256, 0, stream>>>(out, x, x16, pt, pw, ctrl);
  k_gate<<<NTOK / 4, 256, 0, stream>>>(x, Wg, te, tw, ctrl);
  k_scan<<<1, 256, 0, stream>>>(ctrl);
  k_assign<<<NTOK / 256, 256, 0, stream>>>(te, tw, ctrl, pt, pw);

  // W1 [E][1024][4096] -> Wt [E][4096][1024] fp16
  k_transpose<<<dim3(DIN / 128, DHID / 64, NEXP), 256, 0, stream>>>(W1, Wt, DIN, DHID);
  // G1: works = 80 mt x 16 nb (nb-fastest)
  k_gemm<DIN, DHID, 1><<<dim3((DHID / 256) * MAXTILES), 512, 0, stream>>>(
      x16, Wt, b1, ctrl, pt, pw, H, nullptr);

  // W2 [E][4096][1024] -> Wt [E][1024][4096] fp16 (region reuse; stream-ordered)
  k_transpose<<<dim3(DHID / 128, DOUT / 64, NEXP), 256, 0, stream>>>(W2, Wt, DHID, DOUT);
  // G2: works = 80 mt x 4 nb (nb-fastest)
  k_gemm<DHID, DOUT, 0><<<dim3((DOUT / 256) * MAXTILES), 512, 0, stream>>>(
      H, Wt, b2, ctrl, pt, pw, nullptr, out);
}